// Round 5
// baseline (2479.658 us; speedup 1.0000x reference)
//
#include <hip/hip_runtime.h>
#include <hip/hip_bf16.h>

#define Bb 64
#define Tt 256
#define Ii 256
#define Hh 512
#define Cc 1000
#define SENT 0x7F80u  // bf16 +inf; |h|<1 so never produced

typedef float f4 __attribute__((ext_vector_type(4)));
typedef short s8 __attribute__((ext_vector_type(8)));
typedef unsigned long long u64;

__device__ __forceinline__ unsigned short f2bf(float f) {
  union { float f; unsigned u; } v; v.f = f;
  return (unsigned short)((v.u + 0x7FFFu + ((v.u >> 16) & 1u)) >> 16);
}
__device__ __forceinline__ float sigf(float x) {
  return __builtin_amdgcn_rcpf(1.f + __expf(-x));
}
__device__ __forceinline__ float tanhs(float x) {
  float ax = fabsf(x);
  float e = __expf(-2.f * ax);
  float r = (1.f - e) * __builtin_amdgcn_rcpf(1.f + e);
  return copysignf(r, x);
}

struct P4 {
  const float* x;
  const float* Whh[3]; const float* Wih[3];
  const float* bih[3]; const float* bhh[3];
  unsigned short* y[3];
};

// pre-fill all y buffers with the sentinel (sc1 so LLC holds it; pollers read LLC)
__global__ void fill_y(u64* p) {
  const u64 pat = 0x7F807F807F807F80ull;
  size_t g = (size_t)blockIdx.x * 256 + threadIdx.x;
#pragma unroll
  for (int i = 0; i < 16; ++i)
    __hip_atomic_store(p + g + (size_t)i * 393216, pat, __ATOMIC_RELAXED,
                       __HIP_MEMORY_SCOPE_AGENT);
}

__global__ void bias_init_kernel(const float* __restrict__ fcb, float* __restrict__ out) {
  int i = blockIdx.x * 256 + threadIdx.x;
  if (i < Bb * Cc) out[i] = fcb[i % Cc];
}

// 192 blocks = 3 layers x 64 slices (8 h-dims each). Weights live in VGPRs
// (extracted once via LDS staging); t-loop touches LDS only for a 1KB h repack.
// Sync: sentinel-polled sc1 loads of the actual h/y rows; producers never wait.
__launch_bounds__(256, 1)
__global__ void lstm_kernel(P4 p) {
  const int bid = blockIdx.x;
  const int L = bid >> 6;
  const int s = bid & 63;
  const int n0 = s * 8;
  const int tid = threadIdx.x;
  const int lane = tid & 63;
  const int w = tid >> 6;
  const int q = lane >> 4;
  const int c = lane & 15;
  const int b = 16 * w + c;
  const int aswz = (c & 7) << 4;

  __shared__ unsigned short Wst[32 * 512];  // 32KB staging (reused for Whh then Wih)
  __shared__ __align__(16) unsigned short hstage[4][16][8];

  const int Kin = (L == 0) ? Ii : Hh;

  // ---- stage Whh slice (32 gate-rows x 512), extract recurrent A-frags to regs
  {
    const float* src = p.Whh[L];
    for (int idx = tid; idx < 32 * 64; idx += 256) {
      int r = idx >> 6, kk = (idx & 63) << 3;
      int rho = r & 15, tt = r >> 4;
      int j = (rho & 3) * Hh + n0 + 4 * tt + (rho >> 2);
      const float* sr = src + (size_t)j * Hh + kk;
      s8 tv;
#pragma unroll
      for (int e = 0; e < 8; ++e) tv[e] = (short)f2bf(sr[e]);
      int byt = ((r * 512 + kk) * 2) ^ ((r & 7) << 4);
      *(s8*)((char*)Wst + byt) = tv;
    }
  }
  __syncthreads();
  s8 wAr[2][16];
#pragma unroll
  for (int tt = 0; tt < 2; ++tt)
#pragma unroll
    for (int kc = 0; kc < 16; ++kc)
      wAr[tt][kc] = *(const s8*)((const char*)Wst +
                                 ((((tt * 16 + c) * 512 + kc * 32 + 8 * q) * 2) ^ aswz));
  __syncthreads();
  // ---- stage Wih slice, extract input A-frags
  {
    const float* src = p.Wih[L];
    const int kd8 = Kin >> 3;
    for (int idx = tid; idx < 32 * kd8; idx += 256) {
      int r = idx / kd8, kk = (idx - r * kd8) << 3;
      int rho = r & 15, tt = r >> 4;
      int j = (rho & 3) * Hh + n0 + 4 * tt + (rho >> 2);
      const float* sr = src + (size_t)j * Kin + kk;
      s8 tv;
#pragma unroll
      for (int e = 0; e < 8; ++e) tv[e] = (short)f2bf(sr[e]);
      int byt = ((r * Kin + kk) * 2) ^ ((r & 7) << 4);
      *(s8*)((char*)Wst + byt) = tv;
    }
  }
  __syncthreads();
  s8 wAi[2][16];
  if (L == 0) {
#pragma unroll
    for (int tt = 0; tt < 2; ++tt)
#pragma unroll
      for (int kc = 0; kc < 8; ++kc)
        wAi[tt][kc] = *(const s8*)((const char*)Wst +
                                   ((((tt * 16 + c) * 256 + kc * 32 + 8 * q) * 2) ^ aswz));
  } else {
#pragma unroll
    for (int tt = 0; tt < 2; ++tt)
#pragma unroll
      for (int kc = 0; kc < 16; ++kc)
        wAi[tt][kc] = *(const s8*)((const char*)Wst +
                                   ((((tt * 16 + c) * 512 + kc * 32 + 8 * q) * 2) ^ aswz));
  }

  f4 bias2[2];
#pragma unroll
  for (int tt = 0; tt < 2; ++tt)
#pragma unroll
    for (int g = 0; g < 4; ++g) {
      int bi = g * Hh + n0 + 4 * tt + q;
      bias2[tt][g] = p.bih[L][bi] + p.bhh[L][bi];
    }
  float cs0 = 0.f, cs1 = 0.f;

  unsigned short* yl = p.y[L];
  const unsigned short* ylow = (L > 0) ? p.y[L - 1] : (const unsigned short*)0;

  for (int t = 0; t < Tt; ++t) {
    f4 a0 = bias2[0], a1 = bias2[1];

    if (L == 0) {  // input GEMM from x (plain cached loads)
      const float* xr = p.x + ((size_t)b * Tt + t) * Ii + 8 * q;
#pragma unroll
      for (int kc = 0; kc < 8; ++kc) {
        f4 xa = *(const f4*)(xr + kc * 32);
        f4 xc = *(const f4*)(xr + kc * 32 + 4);
        s8 xb;
#pragma unroll
        for (int e = 0; e < 4; ++e) { xb[e] = (short)f2bf(xa[e]); xb[e + 4] = (short)f2bf(xc[e]); }
        a0 = __builtin_amdgcn_mfma_f32_16x16x32_bf16(wAi[0][kc], xb, a0, 0, 0, 0);
        a1 = __builtin_amdgcn_mfma_f32_16x16x32_bf16(wAi[1][kc], xb, a1, 0, 0, 0);
      }
    } else {  // sentinel-poll + load y[L-1] row (b,t); loads ARE the B-frags
      const u64* ip = (const u64*)(ylow + ((size_t)b * Tt + t) * Hh + 8 * q);
      u64 v[32];
      bool ok;
      do {
        ok = true;
#pragma unroll
        for (int kc = 0; kc < 16; ++kc) {
          v[2 * kc] = __hip_atomic_load(ip + 8 * kc, __ATOMIC_RELAXED, __HIP_MEMORY_SCOPE_AGENT);
          v[2 * kc + 1] =
              __hip_atomic_load(ip + 8 * kc + 1, __ATOMIC_RELAXED, __HIP_MEMORY_SCOPE_AGENT);
        }
#pragma unroll
        for (int e = 0; e < 32; ++e) {
          ok &= (((unsigned)v[e]) & 0xFFFFu) != SENT;
          ok &= (((unsigned)(v[e] >> 32)) & 0xFFFFu) != SENT;
        }
        ok = __all(ok);
        if (!ok) __builtin_amdgcn_s_sleep(1);
      } while (!ok);
#pragma unroll
      for (int kc = 0; kc < 16; ++kc) {
        union { u64 u[2]; s8 v8; } cv;
        cv.u[0] = v[2 * kc]; cv.u[1] = v[2 * kc + 1];
        a0 = __builtin_amdgcn_mfma_f32_16x16x32_bf16(wAi[0][kc], cv.v8, a0, 0, 0, 0);
        a1 = __builtin_amdgcn_mfma_f32_16x16x32_bf16(wAi[1][kc], cv.v8, a1, 0, 0, 0);
      }
    }

    if (t > 0) {  // sentinel-poll + load own-layer h[t-1] row (b,t-1)
      const u64* rp = (const u64*)(yl + ((size_t)b * Tt + (t - 1)) * Hh + 8 * q);
      u64 v[32];
      bool ok;
      do {
        ok = true;
#pragma unroll
        for (int kc = 0; kc < 16; ++kc) {
          v[2 * kc] = __hip_atomic_load(rp + 8 * kc, __ATOMIC_RELAXED, __HIP_MEMORY_SCOPE_AGENT);
          v[2 * kc + 1] =
              __hip_atomic_load(rp + 8 * kc + 1, __ATOMIC_RELAXED, __HIP_MEMORY_SCOPE_AGENT);
        }
#pragma unroll
        for (int e = 0; e < 32; ++e) {
          ok &= (((unsigned)v[e]) & 0xFFFFu) != SENT;
          ok &= (((unsigned)(v[e] >> 32)) & 0xFFFFu) != SENT;
        }
        ok = __all(ok);
        if (!ok) __builtin_amdgcn_s_sleep(1);
      } while (!ok);
#pragma unroll
      for (int kc = 0; kc < 16; ++kc) {
        union { u64 u[2]; s8 v8; } cv;
        cv.u[0] = v[2 * kc]; cv.u[1] = v[2 * kc + 1];
        a0 = __builtin_amdgcn_mfma_f32_16x16x32_bf16(wAr[0][kc], cv.v8, a0, 0, 0, 0);
        a1 = __builtin_amdgcn_mfma_f32_16x16x32_bf16(wAr[1][kc], cv.v8, a1, 0, 0, 0);
      }
    }

    // pointwise: lane (q,c): tile tt -> dim n0+4tt+q, gates {i,f,g,o}=acc[0..3]
    {
      float i0 = sigf(a0[0]), f0 = sigf(a0[1]), g0 = tanhs(a0[2]), o0 = sigf(a0[3]);
      cs0 = f0 * cs0 + i0 * g0;
      unsigned short h0 = f2bf(o0 * tanhs(cs0));
      float i1 = sigf(a1[0]), f1 = sigf(a1[1]), g1 = tanhs(a1[2]), o1 = sigf(a1[3]);
      cs1 = f1 * cs1 + i1 * g1;
      unsigned short h1 = f2bf(o1 * tanhs(cs1));
      hstage[w][c][q] = h0;
      hstage[w][c][4 + q] = h1;
    }
    asm volatile("s_waitcnt lgkmcnt(0)" ::: "memory");
    if (lane < 16) {  // repack: one 16B row per batch, two atomic u64 sc1 stores
      const u64* hp = (const u64*)&hstage[w][lane][0];
      u64 lo = hp[0], hi = hp[1];
      u64* dst = (u64*)(yl + ((size_t)(16 * w + lane) * Tt + t) * Hh + n0);
      __hip_atomic_store(dst, lo, __ATOMIC_RELAXED, __HIP_MEMORY_SCOPE_AGENT);
      __hip_atomic_store(dst + 1, hi, __ATOMIC_RELAXED, __HIP_MEMORY_SCOPE_AGENT);
    }
    // no wait — producers stream ahead; consumers poll
  }
}

// out^T-tiled FC: D[c,b] += fc_w[c,k] * y2[b,k]; 32 c-tiles x 32 k-chunks, atomic f32 adds.
__launch_bounds__(256)
__global__ void fc_kernel(const float* __restrict__ w, const unsigned short* __restrict__ y2,
                          float* __restrict__ out) {
  const int ct = blockIdx.x & 31;
  const int kch = blockIdx.x >> 5;
  const int tid = threadIdx.x, lane = tid & 63, wvv = tid >> 6;
  const int b = wvv * 16 + (lane & 15);
  const int KT = Tt * Hh;  // 131072
  const int kbase = kch * 4096 + (lane >> 4) * 8;
  const int c0 = ct * 32 + (lane & 15);
  const int c1 = c0 + 16;
  const bool v0 = (c0 < Cc), v1 = (c1 < Cc);
  const float* w0 = w + (size_t)c0 * KT;
  const float* w1 = w + (size_t)c1 * KT;
  const unsigned short* yr = y2 + (size_t)b * KT;
  f4 a0 = {0.f, 0.f, 0.f, 0.f}, a1 = {0.f, 0.f, 0.f, 0.f};
  for (int kk = 0; kk < 4096; kk += 32) {
    const int k = kbase + kk;
    s8 bf = *(const s8*)(yr + k);
    s8 wa0 = {0, 0, 0, 0, 0, 0, 0, 0}, wa1 = {0, 0, 0, 0, 0, 0, 0, 0};
    if (v0) {
#pragma unroll
      for (int qq = 0; qq < 8; ++qq) wa0[qq] = (short)f2bf(w0[k + qq]);
    }
    if (v1) {
#pragma unroll
      for (int qq = 0; qq < 8; ++qq) wa1[qq] = (short)f2bf(w1[k + qq]);
    }
    a0 = __builtin_amdgcn_mfma_f32_16x16x32_bf16(wa0, bf, a0, 0, 0, 0);
    a1 = __builtin_amdgcn_mfma_f32_16x16x32_bf16(wa1, bf, a1, 0, 0, 0);
  }
  const int rr = (lane >> 4) * 4;
#pragma unroll
  for (int qq = 0; qq < 4; ++qq) {
    int ca = ct * 32 + rr + qq;
    if (ca < Cc) atomicAdd(out + (size_t)b * Cc + ca, a0[qq]);
    int cb2 = ca + 16;
    if (cb2 < Cc) atomicAdd(out + (size_t)b * Cc + cb2, a1[qq]);
  }
}

extern "C" void kernel_launch(void* const* d_in, const int* in_sizes, int n_in,
                              void* d_out, int out_size, void* d_ws, size_t ws_size,
                              hipStream_t stream) {
  P4 p;
  p.x = (const float*)d_in[0];
  p.Wih[0] = (const float*)d_in[1];  p.Whh[0] = (const float*)d_in[2];
  p.bih[0] = (const float*)d_in[3];  p.bhh[0] = (const float*)d_in[4];
  p.Wih[1] = (const float*)d_in[5];  p.Whh[1] = (const float*)d_in[6];
  p.bih[1] = (const float*)d_in[7];  p.bhh[1] = (const float*)d_in[8];
  p.Wih[2] = (const float*)d_in[9];  p.Whh[2] = (const float*)d_in[10];
  p.bih[2] = (const float*)d_in[11]; p.bhh[2] = (const float*)d_in[12];
  const float* fcw = (const float*)d_in[13];
  const float* fcb = (const float*)d_in[14];

  char* ws = (char*)d_ws;
  const size_t ysz = (size_t)Bb * Tt * Hh;  // elems per y buffer (bf16)
  unsigned short* y0 = (unsigned short*)ws;
  p.y[0] = y0;
  p.y[1] = y0 + ysz;
  p.y[2] = y0 + 2 * ysz;

  fill_y<<<1536, 256, 0, stream>>>((u64*)y0);  // 3*ysz*2 bytes = 6291456 u64 exactly
  bias_init_kernel<<<250, 256, 0, stream>>>(fcb, (float*)d_out);
  lstm_kernel<<<192, 256, 0, stream>>>(p);
  fc_kernel<<<1024, 256, 0, stream>>>(fcw, p.y[2], (float*)d_out);
}